// Round 11
// baseline (122.404 us; speedup 1.0000x reference)
//
#include <hip/hip_runtime.h>
#include <cstdint>
#include <cstddef>

#define NB 8
#define NS 2048
#define ND 768
#define NSP 512
#define MAXW 30
#define NH 100
#define LDP 104        // P/CS row stride in floats (26 float4); col 100 = logit/den
#define NKS 24         // 768 / 32 k-steps
#define NCF 8          // 8 col-frags of 16 (cols 0..99 = h, 100 = logit, 101..127 = 0)
#define ASTR 388       // LDS row stride in uints (384 data + 4 pad -> conflict-free)

typedef __attribute__((ext_vector_type(8))) short short8;
typedef __attribute__((ext_vector_type(4))) float floatx4;

union U4S8 { uint4 v; short8 s8; unsigned u[4]; unsigned short us[8]; };

__device__ inline unsigned short f2bf(float f) {
    unsigned u = __float_as_uint(f);
    return (unsigned short)((u + 0x7fffu + ((u >> 16) & 1u)) >> 16);
}

// truncate-split of a float pair into packed bf16x2 hi / lo-residual.
__device__ inline void split2(float x0, float x1, unsigned& hi, unsigned& lo) {
    unsigned u0 = __float_as_uint(x0), u1 = __float_as_uint(x1);
    unsigned h0 = u0 & 0xFFFF0000u, h1 = u1 & 0xFFFF0000u;
    hi = (u0 >> 16) | h1;
    float r0 = x0 - __uint_as_float(h0);
    float r1 = x1 - __uint_as_float(h1);
    lo = (__float_as_uint(r0) >> 16) | (__float_as_uint(r1) & 0xFFFF0000u);
}

// Kernel 0: pack B = [ffnn_w | att_w | 0] (768 x 128) into MFMA B-frag order, bf16.
__global__ __launch_bounds__(256) void pack_b_kernel(
    const float* __restrict__ ffnn_w, const float* __restrict__ att_w,
    uint4* __restrict__ Bfrag)
{
    int ks = blockIdx.x;
    for (int idx = threadIdx.x; idx < NCF * 64; idx += 256) {
        int cf = idx >> 6, lane = idx & 63;
        int q = lane >> 4, r = lane & 15;
        int n = cf * 16 + r;
        U4S8 p;
#pragma unroll
        for (int j = 0; j < 8; j++) {
            int k = ks * 32 + q * 8 + j;
            float v = (n < NH) ? ffnn_w[(size_t)k * NH + n]
                               : (n == NH ? att_w[k] : 0.f);
            p.us[j] = f2bf(v);
        }
        Bfrag[(size_t)(ks * NCF + cf) * 64 + lane] = p.v;
    }
}

// Kernel 1: proj. 1024 blocks x 256 threads. Tile = 16 rows x FULL K=768:
// stage the whole strip as pre-split bf16 hi/lo into LDS (12 independent
// float4 loads/thread -> deep MLP), ONE barrier, then a barrier-free 24-step
// MFMA loop (conflict-free b128 reads, B register-direct from L2, depth-1
// prefetch). Writes P cols 0..100 (col 100 = attention logit).
__global__ __launch_bounds__(256, 3) void proj_kernel(
    const float* __restrict__ seq, const uint4* __restrict__ Bfrag,
    float* __restrict__ P)
{
    __shared__ unsigned Ahi[16 * ASTR];
    __shared__ unsigned Alo[16 * ASTR];
    const int t = threadIdx.x;
    const int wave = t >> 6, lane = t & 63;
    const int q = lane >> 4, r = lane & 15;
    const int cf0 = wave * 2;
    const int row0 = blockIdx.x * 16;

    // staging: thread t owns row tr, float4-chunks tu+16j (j=0..11)
    const int tr = t >> 4, tu = t & 15;
    const float4* gA = (const float4*)(seq + (size_t)(row0 + tr) * ND);
    float4 v[12];
#pragma unroll
    for (int j = 0; j < 12; ++j) v[j] = gA[tu + 16 * j];
#pragma unroll
    for (int j = 0; j < 12; ++j) {
        const int c = tu + 16 * j;
        unsigned h0, l0, h1, l1;
        split2(v[j].x, v[j].y, h0, l0);
        split2(v[j].z, v[j].w, h1, l1);
        uint2 uh; uh.x = h0; uh.y = h1;
        uint2 ul; ul.x = l0; ul.y = l1;
        *(uint2*)&Ahi[tr * ASTR + c * 2] = uh;
        *(uint2*)&Alo[tr * ASTR + c * 2] = ul;
    }
    __syncthreads();   // the only barrier

    floatx4 acc[2] = {{0.f,0.f,0.f,0.f},{0.f,0.f,0.f,0.f}};
    const uint4* bp = Bfrag + (size_t)cf0 * 64 + lane;
    uint4 B0 = bp[0], B1 = bp[64];

    for (int ks = 0; ks < NKS; ++ks) {
        const int nk = (ks + 1 < NKS) ? ks + 1 : ks;
        uint4 N0 = bp[(size_t)nk * 512], N1 = bp[(size_t)nk * 512 + 64];
        U4S8 ah, al, b0, b1;
        ah.v = *(const uint4*)&Ahi[r * ASTR + ks * 16 + q * 4];
        al.v = *(const uint4*)&Alo[r * ASTR + ks * 16 + q * 4];
        b0.v = B0; b1.v = B1;
        acc[0] = __builtin_amdgcn_mfma_f32_16x16x32_bf16(ah.s8, b0.s8, acc[0], 0, 0, 0);
        acc[0] = __builtin_amdgcn_mfma_f32_16x16x32_bf16(al.s8, b0.s8, acc[0], 0, 0, 0);
        acc[1] = __builtin_amdgcn_mfma_f32_16x16x32_bf16(ah.s8, b1.s8, acc[1], 0, 0, 0);
        acc[1] = __builtin_amdgcn_mfma_f32_16x16x32_bf16(al.s8, b1.s8, acc[1], 0, 0, 0);
        B0 = N0; B1 = N1;
    }

    // C/D layout: col = (cf0+c)*16 + r, row = row0 + q*4 + reg
#pragma unroll
    for (int c = 0; c < 2; ++c) {
        const int col = (cf0 + c) * 16 + r;
        if (col <= NH) {
#pragma unroll
            for (int reg = 0; reg < 4; ++reg)
                P[(size_t)(row0 + q * 4 + reg) * LDP + col] = acc[c][reg];
        }
    }
}

// Kernel 2: inclusive prefix-scan along s (per batch) of e^{lg_s} * P[s, 0..99],
// with col-chunk 25 carrying (e^{lg_s}, 0, 0, 0) so scanned col 100 = denominator
// prefix. Grid: 8 batches x 26 chunks; 256 threads x 8 rows each.
__global__ __launch_bounds__(256) void scan_kernel(
    const float* __restrict__ P, float* __restrict__ CS)
{
    __shared__ float4 sm[256];
    const int b = blockIdx.x / 26, chunk = blockIdx.x % 26;
    const int t = threadIdx.x;
    const size_t base = (size_t)b * NS;

    float4 v[8];
#pragma unroll
    for (int i = 0; i < 8; ++i) {
        const int s = t * 8 + i;
        const float* row = P + (base + s) * LDP;
        float el = __expf(row[100]);
        float4 x = *(const float4*)(row + chunk * 4);
        if (chunk == 25) { x.x = el; x.y = 0.f; x.z = 0.f; x.w = 0.f; }
        else { x.x *= el; x.y *= el; x.z *= el; x.w *= el; }
        v[i] = x;
    }
#pragma unroll
    for (int i = 1; i < 8; ++i) {
        v[i].x += v[i-1].x; v[i].y += v[i-1].y;
        v[i].z += v[i-1].z; v[i].w += v[i-1].w;
    }
    sm[t] = v[7];
    __syncthreads();
    for (int off = 1; off < 256; off <<= 1) {
        float4 add = {0.f,0.f,0.f,0.f};
        if (t >= off) add = sm[t - off];
        __syncthreads();
        if (t >= off) {
            float4 cur = sm[t];
            cur.x += add.x; cur.y += add.y; cur.z += add.z; cur.w += add.w;
            sm[t] = cur;
        }
        __syncthreads();
    }
    float4 pre = {0.f,0.f,0.f,0.f};
    if (t > 0) pre = sm[t - 1];
#pragma unroll
    for (int i = 0; i < 8; ++i) {
        float4 o = v[i];
        o.x += pre.x; o.y += pre.y; o.z += pre.z; o.w += pre.w;
        ((float4*)CS)[(base + t * 8 + i) * (LDP / 4) + chunk] = o;
    }
}

// Kernel 3: span epilogue via prefix differences. Half-wave (32 lanes) per span:
// attended·W = (CS[st+w-1] - CS[st-1]) / (den[st+w-1] - den[st-1]);
// out = tanh(mask * attended + bias). Two float4 reads per lane, coalesced.
__global__ __launch_bounds__(256) void span_kernel(
    const int* __restrict__ span_idx, const int* __restrict__ span_mask,
    const float* __restrict__ CS, const float* __restrict__ ffnn_b,
    float* __restrict__ out)
{
    const int hw = threadIdx.x >> 5, lane = threadIdx.x & 31;
    const int gs = blockIdx.x * 8 + hw;            // [0, 4096)
    const int b = gs / NSP;
    const int st = span_idx[2 * gs];
    int w = span_idx[2 * gs + 1] - st;             // width in [1, MAXW]
    w = max(1, min(w, MAXW));

    const int cl = min(lane, 25);
    const float4* cs4 = (const float4*)CS;
    const size_t rb = (size_t)b * NS;
    float4 hi = cs4[(rb + st + w - 1) * (LDP / 4) + cl];
    float4 lo = {0.f, 0.f, 0.f, 0.f};
    if (st > 0) lo = cs4[(rb + st - 1) * (LDP / 4) + cl];  // half-wave-uniform

    float4 d;
    d.x = hi.x - lo.x; d.y = hi.y - lo.y; d.z = hi.z - lo.z; d.w = hi.w - lo.w;
    float den = __shfl(d.x, 25, 32);               // col 100 diff
    float scale = (float)span_mask[gs] / den;

    if (lane < 25) {
        float4 bias = ((const float4*)ffnn_b)[lane];
        float4 o;
        o.x = tanhf(d.x * scale + bias.x);
        o.y = tanhf(d.y * scale + bias.y);
        o.z = tanhf(d.z * scale + bias.z);
        o.w = tanhf(d.w * scale + bias.w);
        *(float4*)(out + (size_t)gs * NH + 4 * lane) = o;
    }
}

extern "C" void kernel_launch(void* const* d_in, const int* in_sizes, int n_in,
                              void* d_out, int out_size, void* d_ws, size_t ws_size,
                              hipStream_t stream) {
    const float* seq      = (const float*)d_in[0];  // [B,S,D]
    const int*   span_idx = (const int*)d_in[1];    // [B,N,2] int32 on device
    const int*   span_msk = (const int*)d_in[2];    // [B,N]
    const float* att_w    = (const float*)d_in[3];  // [D,1]
    // d_in[4] = att_b: cancels inside softmax — unused
    const float* ffnn_w   = (const float*)d_in[5];  // [D,H]
    const float* ffnn_b   = (const float*)d_in[6];  // [H]
    float* out = (float*)d_out;                     // [B,N,H]

    char* ws = (char*)d_ws;
    size_t off = 0;
    float* P     = (float*)(ws + off); off += (size_t)NB * NS * LDP * 4;    // 6.82 MB
    float* CS    = (float*)(ws + off); off += (size_t)NB * NS * LDP * 4;    // 6.82 MB
    uint4* Bfrag = (uint4*)(ws + off);                                      // 192 KB

    pack_b_kernel<<<NKS, 256, 0, stream>>>(ffnn_w, att_w, Bfrag);
    proj_kernel<<<(NB * NS) / 16, 256, 0, stream>>>(seq, Bfrag, P);
    scan_kernel<<<NB * (LDP / 4), 256, 0, stream>>>(P, CS);
    span_kernel<<<(NB * NSP) / 8, 256, 0, stream>>>(span_idx, span_msk, CS, ffnn_b, out);
}

// Round 12
// 117.015 us; speedup vs baseline: 1.0461x; 1.0461x over previous
//
#include <hip/hip_runtime.h>
#include <cstdint>
#include <cstddef>

#define NB 8
#define NS 2048
#define ND 768
#define NSP 512
#define MAXW 30
#define NH 100
#define LDP 104        // P/CS row stride in floats (26 float4); col 100 = logit/den
#define NKS 24         // 768 / 32 k-steps
#define NCF 8          // 8 col-frags of 16 (cols 0..99 = h, 100 = logit, 101..127 = 0)
#define BM 16          // proj rows per block tile
#define NIT 12         // proj outer iters (BK = 64)

typedef __attribute__((ext_vector_type(8))) short short8;
typedef __attribute__((ext_vector_type(4))) float floatx4;

union U4S8 { uint4 v; short8 s8; unsigned u[4]; unsigned short us[8]; };

__device__ inline unsigned short f2bf(float f) {
    unsigned u = __float_as_uint(f);
    return (unsigned short)((u + 0x7fffu + ((u >> 16) & 1u)) >> 16);
}

// truncate-split of a float pair into packed bf16x2 hi / lo-residual.
__device__ inline void split2(float x0, float x1, unsigned& hi, unsigned& lo) {
    unsigned u0 = __float_as_uint(x0), u1 = __float_as_uint(x1);
    unsigned h0 = u0 & 0xFFFF0000u, h1 = u1 & 0xFFFF0000u;
    hi = (u0 >> 16) | h1;
    float r0 = x0 - __uint_as_float(h0);
    float r1 = x1 - __uint_as_float(h1);
    lo = (__float_as_uint(r0) >> 16) | (__float_as_uint(r1) & 0xFFFF0000u);
}

// Kernel 0: pack B = [ffnn_w | att_w | 0] (768 x 128) into MFMA B-frag order, bf16.
__global__ __launch_bounds__(256) void pack_b_kernel(
    const float* __restrict__ ffnn_w, const float* __restrict__ att_w,
    uint4* __restrict__ Bfrag)
{
    int ks = blockIdx.x;
    for (int idx = threadIdx.x; idx < NCF * 64; idx += 256) {
        int cf = idx >> 6, lane = idx & 63;
        int q = lane >> 4, r = lane & 15;
        int n = cf * 16 + r;
        U4S8 p;
#pragma unroll
        for (int j = 0; j < 8; j++) {
            int k = ks * 32 + q * 8 + j;
            float v = (n < NH) ? ffnn_w[(size_t)k * NH + n]
                               : (n == NH ? att_w[k] : 0.f);
            p.us[j] = f2bf(v);
        }
        Bfrag[(size_t)(ks * NCF + cf) * 64 + lane] = p.v;
    }
}

// Kernel 1: proj — R10's proven two-barrier pipeline. 1024 blocks x 256
// threads (16 waves/CU). Tile 16 rows x 128 cols; A pre-split to bf16 hi/lo
// at staging; B register-direct from L2 with depth-1 prefetch.
// Writes P cols 0..100 (col 100 = attention logit, consumed by scan).
__global__ __launch_bounds__(256, 4) void proj_kernel(
    const float* __restrict__ seq, const uint4* __restrict__ Bfrag,
    float* __restrict__ P)
{
    __shared__ unsigned Ahi[BM][36];   // bf16-hi pairs; row stride 144 B
    __shared__ unsigned Alo[BM][36];   // bf16-lo pairs
    const int t = threadIdx.x;
    const int wave = t >> 6, lane = t & 63;
    const int q = lane >> 4, r = lane & 15;
    const int cf0 = wave * 2;
    const int row0 = blockIdx.x * BM;

    floatx4 acc[2] = {{0.f,0.f,0.f,0.f},{0.f,0.f,0.f,0.f}};

    const int sr = t >> 4, sc = t & 15;
    const float4* gA = (const float4*)(seq + (size_t)(row0 + sr) * ND);
    float4 sv = gA[sc];

    const uint4* bp = Bfrag + (size_t)cf0 * 64 + lane;
    uint4 Bc0 = bp[0], Bc1 = bp[64], Bc2 = bp[512], Bc3 = bp[512 + 64];

    for (int i = 0; i < NIT; ++i) {
        unsigned h01, l01, h23, l23;
        split2(sv.x, sv.y, h01, l01);
        split2(sv.z, sv.w, h23, l23);
        __syncthreads();                     // prior iter's LDS reads done
        { uint2 u; u.x = h01; u.y = h23; *(uint2*)&Ahi[sr][sc * 2] = u; }
        { uint2 u; u.x = l01; u.y = l23; *(uint2*)&Alo[sr][sc * 2] = u; }
        __syncthreads();                     // tile i visible

        const int ni = (i + 1 < NIT) ? i + 1 : i;
        sv = gA[ni * 16 + sc];               // prefetch A tile i+1
        const size_t nb = (size_t)ni * 1024;
        uint4 Bn0 = bp[nb], Bn1 = bp[nb + 64], Bn2 = bp[nb + 512], Bn3 = bp[nb + 512 + 64];

#pragma unroll
        for (int ksl = 0; ksl < 2; ++ksl) {
            U4S8 ah, al, b0, b1;
            ah.v = *(const uint4*)&Ahi[r][ksl * 16 + q * 4];
            al.v = *(const uint4*)&Alo[r][ksl * 16 + q * 4];
            b0.v = ksl ? Bc2 : Bc0;
            b1.v = ksl ? Bc3 : Bc1;
            acc[0] = __builtin_amdgcn_mfma_f32_16x16x32_bf16(ah.s8, b0.s8, acc[0], 0, 0, 0);
            acc[0] = __builtin_amdgcn_mfma_f32_16x16x32_bf16(al.s8, b0.s8, acc[0], 0, 0, 0);
            acc[1] = __builtin_amdgcn_mfma_f32_16x16x32_bf16(ah.s8, b1.s8, acc[1], 0, 0, 0);
            acc[1] = __builtin_amdgcn_mfma_f32_16x16x32_bf16(al.s8, b1.s8, acc[1], 0, 0, 0);
        }
        Bc0 = Bn0; Bc1 = Bn1; Bc2 = Bn2; Bc3 = Bn3;
    }

    // C/D layout: col = (cf0+c)*16 + r, row = row0 + q*4 + reg
#pragma unroll
    for (int c = 0; c < 2; ++c) {
        const int col = (cf0 + c) * 16 + r;
        if (col <= NH) {
#pragma unroll
            for (int reg = 0; reg < 4; ++reg)
                P[(size_t)(row0 + q * 4 + reg) * LDP + col] = acc[c][reg];
        }
    }
}

// Kernel 2: inclusive prefix-scan along s of e^{lg_s} * P[s, chunk], chunk 25
// carrying (e^{lg_s},0,0,0) (scanned col 100 = denominator prefix).
// Barrier-light: serial 8-row prefix in regs -> 64-wide shfl_up wave scan
// (no barriers) -> ONE barrier for 4 wave totals. Grid: 8 b x 26 chunks.
__global__ __launch_bounds__(256) void scan_kernel(
    const float* __restrict__ P, float* __restrict__ CS)
{
    __shared__ float4 smw[4];
    const int bidx = blockIdx.x;
    const int b = bidx / 26, chunk = bidx - b * 26;
    const int t = threadIdx.x, lane = t & 63, wv = t >> 6;
    const size_t base = (size_t)b * NS;

    float4 v[8];
#pragma unroll
    for (int i = 0; i < 8; ++i) {
        const int s = t * 8 + i;
        const float* row = P + (base + s) * LDP;
        float el = __expf(row[100]);
        float4 x = *(const float4*)(row + chunk * 4);
        if (chunk == 25) { x.x = el; x.y = 0.f; x.z = 0.f; x.w = 0.f; }
        else { x.x *= el; x.y *= el; x.z *= el; x.w *= el; }
        v[i] = x;
    }
#pragma unroll
    for (int i = 1; i < 8; ++i) {
        v[i].x += v[i-1].x; v[i].y += v[i-1].y;
        v[i].z += v[i-1].z; v[i].w += v[i-1].w;
    }

    // wave-inclusive scan of per-thread totals (64-wide, no barriers)
    float4 tot = v[7];
#pragma unroll
    for (int off = 1; off < 64; off <<= 1) {
        float4 n;
        n.x = __shfl_up(tot.x, off); n.y = __shfl_up(tot.y, off);
        n.z = __shfl_up(tot.z, off); n.w = __shfl_up(tot.w, off);
        if (lane >= off) {
            tot.x += n.x; tot.y += n.y; tot.z += n.z; tot.w += n.w;
        }
    }
    // exclusive per-thread offset = previous lane's inclusive value
    float4 ex;
    ex.x = __shfl_up(tot.x, 1); ex.y = __shfl_up(tot.y, 1);
    ex.z = __shfl_up(tot.z, 1); ex.w = __shfl_up(tot.w, 1);
    if (lane == 0) { ex.x = 0.f; ex.y = 0.f; ex.z = 0.f; ex.w = 0.f; }

    if (lane == 63) smw[wv] = tot;           // wave totals
    __syncthreads();                          // the only barrier
    float4 woff = {0.f, 0.f, 0.f, 0.f};
#pragma unroll
    for (int j = 0; j < 4; ++j) {
        if (j < wv) {
            float4 s = smw[j];
            woff.x += s.x; woff.y += s.y; woff.z += s.z; woff.w += s.w;
        }
    }
    ex.x += woff.x; ex.y += woff.y; ex.z += woff.z; ex.w += woff.w;

#pragma unroll
    for (int i = 0; i < 8; ++i) {
        float4 o = v[i];
        o.x += ex.x; o.y += ex.y; o.z += ex.z; o.w += ex.w;
        ((float4*)CS)[(base + t * 8 + i) * (LDP / 4) + chunk] = o;
    }
}

// Kernel 3: span epilogue via prefix differences. Half-wave per span:
// attended·W = (CS[st+w-1] - CS[st-1]) / (den diff); out = tanh(mask*att + b).
__global__ __launch_bounds__(256) void span_kernel(
    const int* __restrict__ span_idx, const int* __restrict__ span_mask,
    const float* __restrict__ CS, const float* __restrict__ ffnn_b,
    float* __restrict__ out)
{
    const int hw = threadIdx.x >> 5, lane = threadIdx.x & 31;
    const int gs = blockIdx.x * 8 + hw;            // [0, 4096)
    const int b = gs / NSP;
    const int st = span_idx[2 * gs];
    int w = span_idx[2 * gs + 1] - st;             // width in [1, MAXW]
    w = max(1, min(w, MAXW));

    const int cl = min(lane, 25);
    const float4* cs4 = (const float4*)CS;
    const size_t rb = (size_t)b * NS;
    float4 hi = cs4[(rb + st + w - 1) * (LDP / 4) + cl];
    float4 lo = {0.f, 0.f, 0.f, 0.f};
    if (st > 0) lo = cs4[(rb + st - 1) * (LDP / 4) + cl];  // half-wave-uniform

    float4 d;
    d.x = hi.x - lo.x; d.y = hi.y - lo.y; d.z = hi.z - lo.z; d.w = hi.w - lo.w;
    float den = __shfl(d.x, 25, 32);               // col 100 diff
    float scale = (float)span_mask[gs] / den;

    if (lane < 25) {
        float4 bias = ((const float4*)ffnn_b)[lane];
        float4 o;
        o.x = tanhf(d.x * scale + bias.x);
        o.y = tanhf(d.y * scale + bias.y);
        o.z = tanhf(d.z * scale + bias.z);
        o.w = tanhf(d.w * scale + bias.w);
        *(float4*)(out + (size_t)gs * NH + 4 * lane) = o;
    }
}

extern "C" void kernel_launch(void* const* d_in, const int* in_sizes, int n_in,
                              void* d_out, int out_size, void* d_ws, size_t ws_size,
                              hipStream_t stream) {
    const float* seq      = (const float*)d_in[0];  // [B,S,D]
    const int*   span_idx = (const int*)d_in[1];    // [B,N,2] int32 on device
    const int*   span_msk = (const int*)d_in[2];    // [B,N]
    const float* att_w    = (const float*)d_in[3];  // [D,1]
    // d_in[4] = att_b: cancels inside softmax — unused
    const float* ffnn_w   = (const float*)d_in[5];  // [D,H]
    const float* ffnn_b   = (const float*)d_in[6];  // [H]
    float* out = (float*)d_out;                     // [B,N,H]

    char* ws = (char*)d_ws;
    size_t off = 0;
    float* P     = (float*)(ws + off); off += (size_t)NB * NS * LDP * 4;    // 6.82 MB
    float* CS    = (float*)(ws + off); off += (size_t)NB * NS * LDP * 4;    // 6.82 MB
    uint4* Bfrag = (uint4*)(ws + off);                                      // 192 KB

    pack_b_kernel<<<NKS, 256, 0, stream>>>(ffnn_w, att_w, Bfrag);
    proj_kernel<<<(NB * NS) / BM, 256, 0, stream>>>(seq, Bfrag, P);
    scan_kernel<<<NB * (LDP / 4), 256, 0, stream>>>(P, CS);
    span_kernel<<<(NB * NSP) / 8, 256, 0, stream>>>(span_idx, span_msk, CS, ffnn_b, out);
}

// Round 14
// 114.987 us; speedup vs baseline: 1.0645x; 1.0176x over previous
//
#include <hip/hip_runtime.h>
#include <cstdint>
#include <cstddef>

#define NB 8
#define NS 2048
#define ND 768
#define NSP 512
#define MAXW 30
#define NH 100
#define LDP 104        // P row stride in floats (26 float4)
#define NKS 24         // 768 / 32 k-steps
#define NCF 8          // 8 col-frags of 16 (cols 0..99 = h, 100 = logit, 101..127 = 0)
#define BM 16          // proj rows per block tile
#define NIT 12         // proj outer iters (BK = 64)

typedef __attribute__((ext_vector_type(8))) _Float16 half8;
typedef __attribute__((ext_vector_type(2))) __fp16 fp16x2;
typedef __attribute__((ext_vector_type(4))) float floatx4;

union U4H8 { uint4 v; half8 h8; unsigned u[4]; unsigned short us[8]; };
union H2U  { fp16x2 h; unsigned u; };

__device__ inline unsigned short f2h(float f) {   // RNE f32->f16 (pack, cold path)
    _Float16 h = (_Float16)f;
    union { _Float16 hh; unsigned short us; } c; c.hh = h;
    return c.us;
}

// Kernel 0: pack B = [ffnn_w | att_w | 0] (768 x 128) into MFMA B-frag order, f16.
// Frag (ks, cf) at (ks*8+cf)*64: lane l holds B[ks*32 + (l>>4)*8 + j][cf*16 + (l&15)].
__global__ __launch_bounds__(256) void pack_b_kernel(
    const float* __restrict__ ffnn_w, const float* __restrict__ att_w,
    uint4* __restrict__ Bfrag)
{
    int ks = blockIdx.x;
    for (int idx = threadIdx.x; idx < NCF * 64; idx += 256) {
        int cf = idx >> 6, lane = idx & 63;
        int q = lane >> 4, r = lane & 15;
        int n = cf * 16 + r;
        U4H8 p;
#pragma unroll
        for (int j = 0; j < 8; j++) {
            int k = ks * 32 + q * 8 + j;
            float v = (n < NH) ? ffnn_w[(size_t)k * NH + n]
                               : (n == NH ? att_w[k] : 0.f);
            p.us[j] = f2h(v);
        }
        Bfrag[(size_t)(ks * NCF + cf) * 64 + lane] = p.v;
    }
}

// Kernel 1: proj in f16 (single-pass, no hi/lo split). 1024 blocks x 256
// threads (16 waves/CU). Tile 16 rows x 128 cols; A converted f32->f16 via
// v_cvt_pkrtz at staging (1 op / 2 elems) into ONE LDS array (2.3 KB);
// two-barrier pipelined K-loop; B register-direct from L2, depth-1 prefetch.
// Writes P cols 0..99 and Lg (col 100 = attention logit).
__global__ __launch_bounds__(256, 4) void proj_kernel(
    const float* __restrict__ seq, const uint4* __restrict__ Bfrag,
    float* __restrict__ P, float* __restrict__ Lg)
{
    __shared__ unsigned Ah[BM][36];    // f16 pairs; 64 k/row = 32 uints + 4 pad
    const int t = threadIdx.x;
    const int wave = t >> 6, lane = t & 63;
    const int q = lane >> 4, r = lane & 15;
    const int cf0 = wave * 2;
    const int row0 = blockIdx.x * BM;

    floatx4 acc[2] = {{0.f,0.f,0.f,0.f},{0.f,0.f,0.f,0.f}};

    const int sr = t >> 4, sc = t & 15;
    const float4* gA = (const float4*)(seq + (size_t)(row0 + sr) * ND);
    float4 sv = gA[sc];

    const uint4* bp = Bfrag + (size_t)cf0 * 64 + lane;
    uint4 Bc0 = bp[0], Bc1 = bp[64], Bc2 = bp[512], Bc3 = bp[512 + 64];

    for (int i = 0; i < NIT; ++i) {
        H2U u01, u23;
        u01.h = __builtin_amdgcn_cvt_pkrtz(sv.x, sv.y);
        u23.h = __builtin_amdgcn_cvt_pkrtz(sv.z, sv.w);
        __syncthreads();                     // prior iter's LDS reads done
        { uint2 u; u.x = u01.u; u.y = u23.u; *(uint2*)&Ah[sr][sc * 2] = u; }
        __syncthreads();                     // tile i visible

        const int ni = (i + 1 < NIT) ? i + 1 : i;
        sv = gA[ni * 16 + sc];               // prefetch A tile i+1
        const size_t nb = (size_t)ni * 1024;
        uint4 Bn0 = bp[nb], Bn1 = bp[nb + 64], Bn2 = bp[nb + 512], Bn3 = bp[nb + 512 + 64];

#pragma unroll
        for (int ksl = 0; ksl < 2; ++ksl) {
            U4H8 a, b0, b1;
            a.v  = *(const uint4*)&Ah[r][ksl * 16 + q * 4];
            b0.v = ksl ? Bc2 : Bc0;
            b1.v = ksl ? Bc3 : Bc1;
            acc[0] = __builtin_amdgcn_mfma_f32_16x16x32_f16(a.h8, b0.h8, acc[0], 0, 0, 0);
            acc[1] = __builtin_amdgcn_mfma_f32_16x16x32_f16(a.h8, b1.h8, acc[1], 0, 0, 0);
        }
        Bc0 = Bn0; Bc1 = Bn1; Bc2 = Bn2; Bc3 = Bn3;
    }

    // C/D layout: col = (cf0+c)*16 + r, row = row0 + q*4 + reg
#pragma unroll
    for (int c = 0; c < 2; ++c) {
        const int col = (cf0 + c) * 16 + r;
        const int rowb = row0 + q * 4;
        if (col < NH) {
#pragma unroll
            for (int reg = 0; reg < 4; ++reg)
                P[(size_t)(rowb + reg) * LDP + col] = acc[c][reg];
        } else if (col == NH) {
#pragma unroll
            for (int reg = 0; reg < 4; ++reg)
                Lg[rowb + reg] = acc[c][reg];
        }
    }
}

// Kernel 2: TWO spans per wave (half-wave each, width-32 shuffles) -> 2x
// independent load streams per wave. Loads predicated on i<w (half-uniform
// exec mask). Softmax over Lg (att_b cancels); fused bias+mask+tanh.
__global__ __launch_bounds__(256, 4) void span_kernel(
    const int* __restrict__ span_idx, const int* __restrict__ span_mask,
    const float* __restrict__ P, const float* __restrict__ Lg,
    const float* __restrict__ ffnn_b, float* __restrict__ out)
{
    const int hw = threadIdx.x >> 5, lane = threadIdx.x & 31;
    const int gs = blockIdx.x * 8 + hw;            // [0, 4096)
    const int b = gs / NSP;
    const int st = span_idx[2 * gs];
    int w = span_idx[2 * gs + 1] - st;             // width in [1, MAXW]
    w = max(1, min(w, MAXW));

    float lg = (lane < w) ? Lg[b * NS + st + lane] : -1e30f;
    float mx = lg;
#pragma unroll
    for (int off = 16; off > 0; off >>= 1) mx = fmaxf(mx, __shfl_xor(mx, off, 32));
    float e = (lane < w) ? __expf(lg - mx) : 0.f;
    float sum = e;
#pragma unroll
    for (int off = 16; off > 0; off >>= 1) sum += __shfl_xor(sum, off, 32);
    float attn = e / sum;                          // 0 for lanes >= w

    int cl = min(lane, 24);
    const float4* Pb4 = (const float4*)(P + ((size_t)b * NS + st) * LDP) + cl;
    float4 acc = {0.f, 0.f, 0.f, 0.f};
#pragma unroll
    for (int i = 0; i < MAXW; ++i) {
        float a = __shfl(attn, i, 32);
        if (i < w) {                               // half-uniform predicate
            float4 v = Pb4[i * (LDP / 4)];
            acc.x += a * v.x; acc.y += a * v.y; acc.z += a * v.z; acc.w += a * v.w;
        }
    }

    if (lane < 25) {
        float m = (float)span_mask[gs];
        float4 bias = ((const float4*)ffnn_b)[lane];
        float4 o;
        o.x = tanhf(m * acc.x + bias.x);
        o.y = tanhf(m * acc.y + bias.y);
        o.z = tanhf(m * acc.z + bias.z);
        o.w = tanhf(m * acc.w + bias.w);
        *(float4*)(out + (size_t)gs * NH + 4 * lane) = o;
    }
}

extern "C" void kernel_launch(void* const* d_in, const int* in_sizes, int n_in,
                              void* d_out, int out_size, void* d_ws, size_t ws_size,
                              hipStream_t stream) {
    const float* seq      = (const float*)d_in[0];  // [B,S,D]
    const int*   span_idx = (const int*)d_in[1];    // [B,N,2] int32 on device
    const int*   span_msk = (const int*)d_in[2];    // [B,N]
    const float* att_w    = (const float*)d_in[3];  // [D,1]
    // d_in[4] = att_b: cancels inside softmax — unused
    const float* ffnn_w   = (const float*)d_in[5];  // [D,H]
    const float* ffnn_b   = (const float*)d_in[6];  // [H]
    float* out = (float*)d_out;                     // [B,N,H]

    char* ws = (char*)d_ws;
    size_t off = 0;
    float* P     = (float*)(ws + off); off += (size_t)NB * NS * LDP * 4;    // 6.82 MB
    uint4* Bfrag = (uint4*)(ws + off); off += (size_t)NKS * NCF * 64 * 16;  // 192 KB
    float* Lg    = (float*)(ws + off);                                      // 64 KB

    pack_b_kernel<<<NKS, 256, 0, stream>>>(ffnn_w, att_w, Bfrag);
    proj_kernel<<<(NB * NS) / BM, 256, 0, stream>>>(seq, Bfrag, P, Lg);
    span_kernel<<<(NB * NSP) / 8, 256, 0, stream>>>(span_idx, span_msk, P, Lg, ffnn_b, out);
}